// Round 19
// baseline (341.167 us; speedup 1.0000x reference)
//
#include <hip/hip_runtime.h>

using u16 = unsigned short;
using u32 = unsigned int;
typedef __bf16 bf16x8 __attribute__((ext_vector_type(8)));
typedef float f32x4 __attribute__((ext_vector_type(4)));
typedef float f32x16 __attribute__((ext_vector_type(16)));

__device__ __forceinline__ u16 f2bf(float f) {
  u32 u = __float_as_uint(f);
  u += 0x7FFFu + ((u >> 16) & 1u);
  return (u16)(u >> 16);
}

__device__ __forceinline__ u32 cvtpk(float a, float b) {
  u32 r;
  asm("v_cvt_pk_bf16_f32 %0, %1, %2" : "=v"(r) : "v"(a), "v"(b));
  return r;
}

__device__ __forceinline__ void gload16(const u16* g, u16* l) {
  __builtin_amdgcn_global_load_lds((const __attribute__((address_space(1))) void*)g,
                                   (__attribute__((address_space(3))) void*)l, 16, 0, 0);
}

// ---------------- merged prep: a_all + 6 weight transposes ----------------
// blocks [0,1536): a_all; [1536,11776): w4 transposes; [11776,14976): w2.
__global__ void prep_all(const float* __restrict__ enc, const float* __restrict__ ip,
                         u16* __restrict__ a_all,
                         const float* __restrict__ Wk, const float* __restrict__ Wv,
                         const float* __restrict__ Wkip, const float* __restrict__ Wvip,
                         u16* __restrict__ kvw,
                         const float* __restrict__ Wq, const float* __restrict__ Wo,
                         u16* __restrict__ wq_t, u16* __restrict__ wo_t) {
  const int bid = blockIdx.x;
  const int tid = threadIdx.x;
  if (bid < 1536) {
    const int i = bid * 256 + tid;
    const int row = i >> 9;
    const int c4 = i & 511;
    ushort4 o = {0, 0, 0, 0};
    const float4* src = nullptr;
    if (row < 616) src = (const float4*)enc + (size_t)row * 512 + c4;
    else if (row >= 640 && row < 672) src = (const float4*)ip + (size_t)(row - 640) * 512 + c4;
    if (src) {
      const float4 v = *src;
      o.x = f2bf(v.x); o.y = f2bf(v.y); o.z = f2bf(v.z); o.w = f2bf(v.w);
    }
    ((ushort4*)a_all)[i] = o;
    return;
  }
  __shared__ float tile[32][33];
  const int x = tid & 31, y = tid >> 5;  // (32, 8)
  const float* in;
  u16* out;
  int K, N, n0, k0;
  if (bid < 11776) {
    const int f = bid - 1536;  // 10240 = 4 x (40 x 64)
    const int z = f / 2560, rem = f % 2560;
    in = (z == 0) ? Wk : (z == 1) ? Wv : (z == 2) ? Wkip : Wvip;
    out = kvw + (size_t)z * 1280 * 2048;
    K = 2048; N = 1280;
    n0 = (rem % 40) << 5; k0 = (rem / 40) << 5;
  } else {
    const int f = bid - 11776;  // 3200 = 2 x (40 x 40)
    const int z = f / 1600, rem = f % 1600;
    in = z ? Wo : Wq;
    out = z ? wo_t : wq_t;
    K = 1280; N = 1280;
    n0 = (rem % 40) << 5; k0 = (rem / 40) << 5;
  }
#pragma unroll
  for (int i = 0; i < 32; i += 8)
    tile[y + i][x] = in[(size_t)(k0 + y + i) * N + n0 + x];
  __syncthreads();
#pragma unroll
  for (int i = 0; i < 32; i += 8)
    out[(size_t)(n0 + y + i) * K + k0 + x] = f2bf(tile[x][y + i]);
}

#define MFMA16(a, b, c) __builtin_amdgcn_mfma_f32_16x16x32_bf16(a, b, c, 0, 0, 0)
#define MFMA32(a, b, c) __builtin_amdgcn_mfma_f32_32x32x16_bf16(a, b, c, 0, 0, 0)

// -------- 256x256 pipelined GEMM (KV projections) + conv overlay --------
// Blocks >= 60 run the hs f32->bf16 convert (overlaps BW with GEMM).
__global__ __launch_bounds__(512, 2) void gemm256kv(
    const u16* __restrict__ A, const u16* __restrict__ Bt, u16* __restrict__ Cb,
    const float* __restrict__ convSrc, u16* __restrict__ convDst,
    int M, int N, int K) {
  const int tid = threadIdx.x;

  if (blockIdx.x >= 60) {
    const float4* src = (const float4*)convSrc;
    ushort4* dst = (ushort4*)convDst;
    const long base = (long)(blockIdx.x - 60) * 4096 + tid;
#pragma unroll
    for (int k = 0; k < 8; ++k) {
      const float4 v = src[base + k * 512];
      ushort4 o;
      o.x = f2bf(v.x); o.y = f2bf(v.y); o.z = f2bf(v.z); o.w = f2bf(v.w);
      dst[base + k * 512] = o;
    }
    return;
  }

  __shared__ __align__(16) u16 smem[65536];
  u16* As = smem;
  u16* Bs = smem + 32768;

  const int w = tid >> 6, lane = tid & 63;
  const int lo = lane & 15, hi = lane >> 4;
  const int wm = w >> 2, wn = w & 3;

  const int nbn = N >> 8;
  const int wg = blockIdx.x;
  const int bm = wg / nbn, bn = wg % nbn;
  const int m0 = bm << 8, n0 = bn << 8;
  const int NT = K >> 6;

  const int sr = lane >> 3;
  const int sc8 = ((lane & 7) ^ sr) << 3;
  const u16* pA[2];
  const u16* pB[2];
#pragma unroll
  for (int i = 0; i < 2; ++i) {
    const int rr = (i * 8 + w) * 8 + sr;
    pA[i] = A + (size_t)(m0 + rr) * K + sc8;
    pB[i] = Bt + (size_t)(n0 + rr) * K + sc8;
  }
  const int ch0 = w * 512, ch1 = (8 + w) * 512;

#define STAGE_A(h, tt)                                                     \
  {                                                                        \
    const int ttc = ((tt) < NT) ? (tt) : (NT - 1);                         \
    u16* d = As + ((((tt)&1) * 2 + (h)) << 13);                            \
    const size_t off = (size_t)(h)*128 * K + (size_t)ttc * 64;             \
    gload16(pA[0] + off, d + ch0);                                         \
    gload16(pA[1] + off, d + ch1);                                         \
  }
#define STAGE_B(h, tt)                                                     \
  {                                                                        \
    const int ttc = ((tt) < NT) ? (tt) : (NT - 1);                         \
    u16* d = Bs + ((((tt)&1) * 2 + (h)) << 13);                            \
    const size_t off = (size_t)(h)*128 * K + (size_t)ttc * 64;             \
    gload16(pB[0] + off, d + ch0);                                         \
    gload16(pB[1] + off, d + ch1);                                         \
  }

  const int low0 = (lo << 7) | ((hi ^ (lo & 7)) << 4);
  const int low1 = (lo << 7) | (((4 | hi) ^ (lo & 7)) << 4);

  f32x4 acc[8][4];
#pragma unroll
  for (int i = 0; i < 8; ++i)
#pragma unroll
    for (int j = 0; j < 4; ++j) acc[i][j] = (f32x4){0.f, 0.f, 0.f, 0.f};

  STAGE_B(0, 0); STAGE_B(1, 0);
  STAGE_A(0, 0); STAGE_A(1, 0);
  STAGE_B(0, 1); STAGE_B(1, 1);

  const char* aSm = (const char*)As;
  const char* bSm = (const char*)Bs;

  for (int t = 0; t < NT; ++t) {
    const int p = t & 1;
    const int aBase = (p * 2 + wm) << 14;
    const int bBase = ((p * 2 + (wn >> 1)) << 14) + ((wn & 1) << 13);

    asm volatile("s_waitcnt vmcnt(4)" ::: "memory");
    asm volatile("s_barrier" ::: "memory");

    bf16x8 a0[4][2], a1[4][2], b0[2][2], b1[2][2];
#pragma unroll
    for (int mf = 0; mf < 4; ++mf) {
      a0[mf][0] = *(const bf16x8*)(aSm + aBase + (mf << 11) + low0);
      a0[mf][1] = *(const bf16x8*)(aSm + aBase + (mf << 11) + low1);
    }
#pragma unroll
    for (int nf = 0; nf < 2; ++nf) {
      b0[nf][0] = *(const bf16x8*)(bSm + bBase + (nf << 11) + low0);
      b0[nf][1] = *(const bf16x8*)(bSm + bBase + (nf << 11) + low1);
    }
    STAGE_A(0, t + 1);
    __builtin_amdgcn_s_setprio(1);
#pragma unroll
    for (int mf = 0; mf < 4; ++mf)
#pragma unroll
      for (int nf = 0; nf < 2; ++nf) {
        acc[mf][nf] = MFMA16(a0[mf][0], b0[nf][0], acc[mf][nf]);
        acc[mf][nf] = MFMA16(a0[mf][1], b0[nf][1], acc[mf][nf]);
      }
    __builtin_amdgcn_s_setprio(0);

#pragma unroll
    for (int nf = 0; nf < 2; ++nf) {
      b1[nf][0] = *(const bf16x8*)(bSm + bBase + (1 << 12) + (nf << 11) + low0);
      b1[nf][1] = *(const bf16x8*)(bSm + bBase + (1 << 12) + (nf << 11) + low1);
    }
    STAGE_A(1, t + 1);
    __builtin_amdgcn_s_setprio(1);
#pragma unroll
    for (int mf = 0; mf < 4; ++mf)
#pragma unroll
      for (int nf = 0; nf < 2; ++nf) {
        acc[mf][2 + nf] = MFMA16(a0[mf][0], b1[nf][0], acc[mf][2 + nf]);
        acc[mf][2 + nf] = MFMA16(a0[mf][1], b1[nf][1], acc[mf][2 + nf]);
      }
    __builtin_amdgcn_s_setprio(0);
    asm volatile("s_barrier" ::: "memory");

#pragma unroll
    for (int mf = 0; mf < 4; ++mf) {
      a1[mf][0] = *(const bf16x8*)(aSm + aBase + (1 << 13) + (mf << 11) + low0);
      a1[mf][1] = *(const bf16x8*)(aSm + aBase + (1 << 13) + (mf << 11) + low1);
    }
    STAGE_B(0, t + 2);
    __builtin_amdgcn_s_setprio(1);
#pragma unroll
    for (int mf = 0; mf < 4; ++mf)
#pragma unroll
      for (int nf = 0; nf < 2; ++nf) {
        acc[4 + mf][nf] = MFMA16(a1[mf][0], b0[nf][0], acc[4 + mf][nf]);
        acc[4 + mf][nf] = MFMA16(a1[mf][1], b0[nf][1], acc[4 + mf][nf]);
      }
    __builtin_amdgcn_s_setprio(0);

    STAGE_B(1, t + 2);
    __builtin_amdgcn_s_setprio(1);
#pragma unroll
    for (int mf = 0; mf < 4; ++mf)
#pragma unroll
      for (int nf = 0; nf < 2; ++nf) {
        acc[4 + mf][2 + nf] = MFMA16(a1[mf][0], b1[nf][0], acc[4 + mf][2 + nf]);
        acc[4 + mf][2 + nf] = MFMA16(a1[mf][1], b1[nf][1], acc[4 + mf][2 + nf]);
      }
    __builtin_amdgcn_s_setprio(0);
  }

#pragma unroll
  for (int g = 0; g < 2; ++g)
#pragma unroll
    for (int mf = 0; mf < 4; ++mf)
#pragma unroll
      for (int ng = 0; ng < 2; ++ng)
#pragma unroll
        for (int nfi = 0; nfi < 2; ++nfi) {
          const f32x4 v = acc[g * 4 + mf][ng * 2 + nfi];
          const int row0 = m0 + wm * 128 + g * 64 + mf * 16 + hi * 4;
          const int col = n0 + wn * 64 + ng * 32 + nfi * 16 + lo;
#pragma unroll
          for (int r = 0; r < 4; ++r)
            Cb[(size_t)(row0 + r) * N + col] = f2bf(v[r]);
        }
#undef STAGE_A
#undef STAGE_B
}

// ---------------- 128x128 GEMM, 2 blocks/CU ----------------
// MODE 1: C -> f32 + bias (O-proj).  MODE 2: fused attention epilogue,
// sequential per-32-query group (low register pressure); wave (wm,wn)
// owns 64 queries x head 2*bn+wn; K/V fragments from coalesced kt2/vt2.
// Iteration: vmcnt(8)+bar -> ds_reads -> lgkmcnt(0)+bar -> STG(t+2) -> MFMA.
template <int MODE>
__global__ __launch_bounds__(256, 2) void gemm128(
    const u16* __restrict__ A, const u16* __restrict__ Bt,
    u16* __restrict__ Cb, float* __restrict__ Cf, const float* __restrict__ bias,
    const u16* __restrict__ ktP, const u16* __restrict__ vtP,
    int M, int N, int K) {
  __shared__ __align__(16) u16 smem[32768];  // As 32KB | Bs 32KB
  const int tid = threadIdx.x;
  const int w = tid >> 6, lane = tid & 63;
  const int lo = lane & 15, hi = lane >> 4;
  const int wm = w >> 1, wn = w & 1;

  const int nbn = N >> 7;
  int wg = blockIdx.x;
  {  // bijective XCD swizzle
    const int nwg = gridDim.x;
    const int q = nwg >> 3, r = nwg & 7;
    const int xcd = wg & 7, l = wg >> 3;
    wg = (xcd < r ? xcd * (q + 1) : r * (q + 1) + (xcd - r) * q) + l;
  }
  const int bm = wg / nbn, bn = wg % nbn;
  const int m0 = bm << 7, n0 = bn << 7;
  const int NT = K >> 6;

  const int sr = lane >> 3;
  const int sc8 = ((lane & 7) ^ sr) << 3;
  const u16 *pA[4], *pB[4];
#pragma unroll
  for (int j = 0; j < 4; ++j) {
    const int rr = (w + j * 4) * 8 + sr;
    pA[j] = A + (size_t)(m0 + rr) * K + sc8;
    pB[j] = Bt + (size_t)(n0 + rr) * K + sc8;
  }

#define STG128(tt)                                                         \
  {                                                                        \
    const int ttc = ((tt) < NT) ? (tt) : (NT - 1);                         \
    const int bofs = (((tt)&1) << 13); /* u16 units: buf * 8192 */         \
    const size_t off = (size_t)ttc * 64;                                   \
    _Pragma("unroll") for (int j = 0; j < 4; ++j) {                        \
      gload16(pA[j] + off, smem + bofs + (w + j * 4) * 512);               \
      gload16(pB[j] + off, smem + 16384 + bofs + (w + j * 4) * 512);       \
    }                                                                      \
  }

  const int low0 = (lo << 7) | ((hi ^ (lo & 7)) << 4);
  const int low1 = (lo << 7) | (((4 | hi) ^ (lo & 7)) << 4);
  const char* aSm = (const char*)smem;
  const char* bSm = (const char*)(smem + 16384);

  f32x4 acc[4][4];
#pragma unroll
  for (int i = 0; i < 4; ++i)
#pragma unroll
    for (int j = 0; j < 4; ++j) acc[i][j] = (f32x4){0.f, 0.f, 0.f, 0.f};

  STG128(0); STG128(1);

  for (int t = 0; t < NT; ++t) {
    const int aBase = ((t & 1) << 14) + (wm << 13);
    const int bBase = ((t & 1) << 14) + (wn << 13);

    asm volatile("s_waitcnt vmcnt(8)" ::: "memory");
    asm volatile("s_barrier" ::: "memory");

    bf16x8 a[4][2], b[4][2];
#pragma unroll
    for (int mf = 0; mf < 4; ++mf) {
      a[mf][0] = *(const bf16x8*)(aSm + aBase + (mf << 11) + low0);
      a[mf][1] = *(const bf16x8*)(aSm + aBase + (mf << 11) + low1);
    }
#pragma unroll
    for (int nf = 0; nf < 4; ++nf) {
      b[nf][0] = *(const bf16x8*)(bSm + bBase + (nf << 11) + low0);
      b[nf][1] = *(const bf16x8*)(bSm + bBase + (nf << 11) + low1);
    }
    // All reads must land before any wave restages this buffer (WAR).
    asm volatile("s_waitcnt lgkmcnt(0)" ::: "memory");
    __builtin_amdgcn_sched_barrier(0);
    asm volatile("s_barrier" ::: "memory");
    STG128(t + 2);
    __builtin_amdgcn_s_setprio(1);
#pragma unroll
    for (int mf = 0; mf < 4; ++mf)
#pragma unroll
      for (int nf = 0; nf < 4; ++nf) {
        acc[mf][nf] = MFMA16(a[mf][0], b[nf][0], acc[mf][nf]);
        acc[mf][nf] = MFMA16(a[mf][1], b[nf][1], acc[mf][nf]);
      }
    __builtin_amdgcn_s_setprio(0);
  }

  if (MODE == 1) {
    // ---- f32 + bias epilogue ----
#pragma unroll
    for (int mf = 0; mf < 4; ++mf)
#pragma unroll
      for (int nf = 0; nf < 4; ++nf) {
        const int row0 = m0 + wm * 64 + mf * 16 + hi * 4;
        const int col = n0 + wn * 64 + nf * 16 + lo;
        const float bb = bias[col];
#pragma unroll
        for (int r = 0; r < 4; ++r)
          Cf[(size_t)(row0 + r) * N + col] = acc[mf][nf][r] + bb;
      }
  } else {
    // ---- fused attention epilogue, sequential 32-query groups ----
    const int l31 = lane & 31, hi5 = lane >> 5;
    const int h = bn * 2 + wn;       // this wave's head
    const int b = m0 >> 12;          // batch (4096 rows per batch)
    const u16* ktb = ktP + (size_t)(b * 20 + h) * 6144;
    const u16* vtb = vtP + (size_t)(b * 20 + h) * 6144;

    // K fragments: coalesced; latency hides under drain + Q-LDS writes.
    bf16x8 kreg[3][4];
#pragma unroll
    for (int kf = 0; kf < 3; ++kf)
#pragma unroll
      for (int dc = 0; dc < 4; ++dc)
        kreg[kf][dc] = *(const bf16x8*)(ktb + (((kf << 2) | dc) << 9) + lane * 8);

    // Drain in-flight global_load_lds (would corrupt Q-LDS), sync all waves.
    asm volatile("s_waitcnt vmcnt(0)" ::: "memory");
    __builtin_amdgcn_s_barrier();

    // Wave-private Q chunk: [64 q][64 d], stride 66 u16.
    u16* qlds = smem + w * 4224;
#pragma unroll
    for (int mf = 0; mf < 4; ++mf)
#pragma unroll
      for (int nf = 0; nf < 4; ++nf) {
        const f32x4 v = acc[mf][nf];
        const int qrow = mf * 16 + hi * 4;
        const int d = nf * 16 + lo;
#pragma unroll
        for (int r = 0; r < 4; ++r) qlds[(qrow + r) * 66 + d] = f2bf(v[r]);
      }
    asm volatile("s_waitcnt lgkmcnt(0)" ::: "memory");
    __builtin_amdgcn_sched_barrier(0);

    const int rowB = m0 + wm * 64;

#pragma unroll 1
    for (int grp = 0; grp < 2; ++grp) {
      bf16x8 qf[4];
#pragma unroll
      for (int dc = 0; dc < 4; ++dc)
        qf[dc] = *(const bf16x8*)&qlds[(grp * 32 + l31) * 66 + dc * 16 + hi5 * 8];

      f32x16 s[3];
#pragma unroll
      for (int kf = 0; kf < 3; ++kf)
#pragma unroll
        for (int r = 0; r < 16; ++r) s[kf][r] = 0.f;

#pragma unroll
      for (int kf = 0; kf < 3; ++kf)
#pragma unroll
        for (int dc = 0; dc < 4; ++dc) s[kf] = MFMA32(kreg[kf][dc], qf[dc], s[kf]);

      float st = 0.f, si = 0.f;
#pragma unroll
      for (int kf = 0; kf < 3; ++kf)
#pragma unroll
        for (int r = 0; r < 16; ++r) {
          const int krem = (r & 3) + 8 * (r >> 2);
          const int k = kf * 32 + krem + 4 * hi5;
          const bool vtx = k < 77;
          const bool vip = (k >= 80) & (k < 84);
          const float e = (vtx | vip) ? __expf(s[kf][r] * 0.125f) : 0.f;
          s[kf][r] = e;
          st += vtx ? e : 0.f;
          si += vip ? e : 0.f;
        }
      st += __shfl_xor(st, 32);
      si += __shfl_xor(si, 32);
      const float rt = __fdividef(1.f, st);
      const float ri = __fdividef(1.f, si);
#pragma unroll
      for (int kf = 0; kf < 3; ++kf)
#pragma unroll
        for (int r = 0; r < 16; ++r) {
          const int krem = (r & 3) + 8 * (r >> 2);
          const int k = kf * 32 + krem + 4 * hi5;
          const bool vip = (k >= 80) & (k < 84);
          s[kf][r] *= vip ? ri : rt;
        }

      f32x16 pacc[2];
#pragma unroll
      for (int nf = 0; nf < 2; ++nf)
#pragma unroll
        for (int r = 0; r < 16; ++r) pacc[nf][r] = 0.f;
#pragma unroll
      for (int ks = 0; ks < 6; ++ks) {
        const int kf = ks >> 1;
        const int rb = (ks & 1) * 8;
        const u32 lo01 = cvtpk(s[kf][rb + 0], s[kf][rb + 1]);
        const u32 lo23 = cvtpk(s[kf][rb + 2], s[kf][rb + 3]);
        const u32 hi01 = cvtpk(s[kf][rb + 4], s[kf][rb + 5]);
        const u32 hi23 = cvtpk(s[kf][rb + 6], s[kf][rb + 7]);
        const u32 plo01 = __shfl_xor(lo01, 32);
        const u32 plo23 = __shfl_xor(lo23, 32);
        const u32 phi01 = __shfl_xor(hi01, 32);
        const u32 phi23 = __shfl_xor(hi23, 32);
        union { u32 u[4]; bf16x8 v; } pu;
        pu.u[0] = hi5 ? phi01 : lo01;
        pu.u[1] = hi5 ? phi23 : lo23;
        pu.u[2] = hi5 ? hi01 : plo01;
        pu.u[3] = hi5 ? hi23 : plo23;
#pragma unroll
        for (int nf = 0; nf < 2; ++nf) {
          const bf16x8 vb = *(const bf16x8*)(vtb +
              ((((hi5 * 2 + nf) * 6 + ks) * 32 + l31) << 3));
          pacc[nf] = MFMA32(pu.v, vb, pacc[nf]);
        }
      }
#pragma unroll
      for (int nf = 0; nf < 2; ++nf)
#pragma unroll
        for (int r = 0; r < 16; ++r) {
          const int row = rowB + grp * 32 + (r & 3) + 8 * (r >> 2) + 4 * hi5;
          Cb[(size_t)row * 1280 + h * 64 + nf * 32 + l31] = f2bf(pacc[nf][r]);
        }
    }
  }
#undef STG128
}

// ------- build_kvt: lane-coalesced K/V fragment buffers per (b,h) -------
// kt2[bh][kf(3)][dc(4)][lane(64)][8]: = K[kf*32+(lane&31)][dc*16+(lane>>5)*8 + j]
// vt2[bh][hi5(2)][nf(2)][ks(6)][l31(32)][8]: = V[ks*16+hi5*8+j][nf*32+l31]
__global__ __launch_bounds__(256) void build_kvt(const u16* __restrict__ kvc,
                                                 u16* __restrict__ kt2,
                                                 u16* __restrict__ vt2) {
  __shared__ u16 Ls[96][72];
  const int tid = threadIdx.x;
  const int h = blockIdx.x % 20, b = blockIdx.x / 20;

  for (int idx = tid; idx < 96 * 8; idx += 256) {
    const int row = idx >> 3, c8 = (idx & 7) << 3;
    uint4 val = make_uint4(0, 0, 0, 0);
    if (row < 77)
      val = *(const uint4*)(kvc + (size_t)(b * 77 + row) * 5120 + 1280 + h * 64 + c8);
    else if (row >= 80 && row < 84)
      val = *(const uint4*)(kvc + (size_t)(640 + b * 4 + row - 80) * 5120 + 3840 + h * 64 + c8);
    *(uint4*)&Ls[row][c8] = val;
  }

  u16* kdst = kt2 + (size_t)blockIdx.x * 6144;
  for (int idx = tid; idx < 768; idx += 256) {
    const int lane_ = idx & 63;
    const int rest = idx >> 6;          // 0..11
    const int dc = rest & 3, kf = rest >> 2;
    const int key = kf * 32 + (lane_ & 31);
    const int dofs = dc * 16 + (lane_ >> 5) * 8;
    const u16* src;
    if (key < 77) src = kvc + (size_t)(b * 77 + key) * 5120 + h * 64 + dofs;
    else if (key >= 80 && key < 84)
      src = kvc + (size_t)(640 + b * 4 + key - 80) * 5120 + 2560 + h * 64 + dofs;
    else src = kvc + h * 64 + dofs;  // masked later; finite garbage ok
    *(uint4*)(kdst + idx * 8) = *(const uint4*)src;
  }
  __syncthreads();

  u16* vdst = vt2 + (size_t)blockIdx.x * 6144;
  for (int idx = tid; idx < 768; idx += 256) {
    const int l31 = idx & 31;
    const int rest = idx >> 5;          // 0..23
    const int ks = rest % 6;
    const int t = rest / 6;             // 0..3
    const int nf = t & 1, hi5 = t >> 1;
    u16 tmp[8];
#pragma unroll
    for (int j = 0; j < 8; ++j) tmp[j] = Ls[ks * 16 + hi5 * 8 + j][nf * 32 + l31];
    *(uint4*)(vdst + (((size_t)(hi5 * 2 + nf) * 6 + ks) * 32 + l31) * 8) = *(const uint4*)tmp;
  }
}

// ---------------- launch ----------------
extern "C" void kernel_launch(void* const* d_in, const int* in_sizes, int n_in,
                              void* d_out, int out_size, void* d_ws, size_t ws_size,
                              hipStream_t stream) {
  (void)in_sizes; (void)n_in; (void)out_size; (void)ws_size;
  const float* hs   = (const float*)d_in[0];
  const float* enc  = (const float*)d_in[1];
  const float* ip   = (const float*)d_in[2];
  const float* Wq   = (const float*)d_in[3];
  const float* Wk   = (const float*)d_in[4];
  const float* Wv   = (const float*)d_in[5];
  const float* Wkip = (const float*)d_in[6];
  const float* Wvip = (const float*)d_in[7];
  const float* Wo   = (const float*)d_in[8];
  const float* bo   = (const float*)d_in[9];
  float* out = (float*)d_out;

  // d_out (167.8 MB) as scratch: wq_t at start, hs_bf in second half
  // (both dead before the final f32 output write by O-proj).
  u16* wq_t  = (u16*)d_out;                        // 3,276,800 B
  u16* hs_bf = (u16*)d_out + 41943040;             // 83,886,080 B

  // ws layout. kvw/a_all overlap the attn region (dead before fused kernel).
  char* ws = (char*)d_ws;
  u16* kvc   = (u16*)(ws);                          // 15,728,640 B  [768][5120]
  u16* wo_t  = (u16*)(ws + 15728640);               //  3,276,800 B
  u16* kt2   = (u16*)(ws + 19005440);               //  1,966,080 B  [160][6144]
  u16* vt2   = (u16*)(ws + 20971520);               //  1,966,080 B  [160][6144]
  u16* attn  = (u16*)(ws + 22937600);               // 83,886,080 B
  u16* kvw   = (u16*)(ws + 22937600 + 3276800);     // 20,971,520 B (overlap) [5120][2048]
  u16* a_all = (u16*)(ws + 22937600 + 24248320);    //  3,145,728 B (overlap) [768][2048]

  // merged prep: a_all + 4x w4-transpose + 2x w2-transpose
  prep_all<<<14976, 256, 0, stream>>>(enc, ip, a_all, Wk, Wv, Wkip, Wvip, kvw,
                                      Wq, Wo, wq_t, wo_t);

  // fused K/V projections (blocks 0..59) + hs f32->bf16 convert (blocks 60..2619)
  gemm256kv<<<2620, 512, 0, stream>>>(a_all, kvw, kvc, hs, hs_bf, 768, 5120, 2048);
  build_kvt<<<160, 256, 0, stream>>>(kvc, kt2, vt2);

  // Q-proj + attention fused (128^2 tile, 2 blocks/CU): writes attn directly
  gemm128<2><<<2560, 256, 0, stream>>>(hs_bf, wq_t, attn, nullptr, nullptr,
                                       kt2, vt2, 32768, 1280, 1280);

  // O-proj + bias (f32 out): 128^2 tile, 2 blocks/CU, zero grid tail
  gemm128<1><<<2560, 256, 0, stream>>>(attn, wo_t, nullptr, out, bo,
                                       nullptr, nullptr, 32768, 1280, 1280);
}

// Round 20
// 324.464 us; speedup vs baseline: 1.0515x; 1.0515x over previous
//
#include <hip/hip_runtime.h>

using u16 = unsigned short;
using u32 = unsigned int;
typedef __bf16 bf16x8 __attribute__((ext_vector_type(8)));
typedef float f32x4 __attribute__((ext_vector_type(4)));
typedef float f32x16 __attribute__((ext_vector_type(16)));

__device__ __forceinline__ u16 f2bf(float f) {
  u32 u = __float_as_uint(f);
  u += 0x7FFFu + ((u >> 16) & 1u);
  return (u16)(u >> 16);
}

__device__ __forceinline__ u32 cvtpk(float a, float b) {
  u32 r;
  asm("v_cvt_pk_bf16_f32 %0, %1, %2" : "=v"(r) : "v"(a), "v"(b));
  return r;
}

__device__ __forceinline__ void gload16(const u16* g, u16* l) {
  __builtin_amdgcn_global_load_lds((const __attribute__((address_space(1))) void*)g,
                                   (__attribute__((address_space(3))) void*)l, 16, 0, 0);
}

// ---------------- merged prep: a_all + 6 weight transposes ----------------
// blocks [0,1536): a_all; [1536,11776): w4 transposes; [11776,14976): w2.
__global__ void prep_all(const float* __restrict__ enc, const float* __restrict__ ip,
                         u16* __restrict__ a_all,
                         const float* __restrict__ Wk, const float* __restrict__ Wv,
                         const float* __restrict__ Wkip, const float* __restrict__ Wvip,
                         u16* __restrict__ kvw,
                         const float* __restrict__ Wq, const float* __restrict__ Wo,
                         u16* __restrict__ wq_t, u16* __restrict__ wo_t) {
  const int bid = blockIdx.x;
  const int tid = threadIdx.x;
  if (bid < 1536) {
    const int i = bid * 256 + tid;
    const int row = i >> 9;
    const int c4 = i & 511;
    ushort4 o = {0, 0, 0, 0};
    const float4* src = nullptr;
    if (row < 616) src = (const float4*)enc + (size_t)row * 512 + c4;
    else if (row >= 640 && row < 672) src = (const float4*)ip + (size_t)(row - 640) * 512 + c4;
    if (src) {
      const float4 v = *src;
      o.x = f2bf(v.x); o.y = f2bf(v.y); o.z = f2bf(v.z); o.w = f2bf(v.w);
    }
    ((ushort4*)a_all)[i] = o;
    return;
  }
  __shared__ float tile[32][33];
  const int x = tid & 31, y = tid >> 5;  // (32, 8)
  const float* in;
  u16* out;
  int K, N, n0, k0;
  if (bid < 11776) {
    const int f = bid - 1536;  // 10240 = 4 x (40 x 64)
    const int z = f / 2560, rem = f % 2560;
    in = (z == 0) ? Wk : (z == 1) ? Wv : (z == 2) ? Wkip : Wvip;
    out = kvw + (size_t)z * 1280 * 2048;
    K = 2048; N = 1280;
    n0 = (rem % 40) << 5; k0 = (rem / 40) << 5;
  } else {
    const int f = bid - 11776;  // 3200 = 2 x (40 x 40)
    const int z = f / 1600, rem = f % 1600;
    in = z ? Wo : Wq;
    out = z ? wo_t : wq_t;
    K = 1280; N = 1280;
    n0 = (rem % 40) << 5; k0 = (rem / 40) << 5;
  }
#pragma unroll
  for (int i = 0; i < 32; i += 8)
    tile[y + i][x] = in[(size_t)(k0 + y + i) * N + n0 + x];
  __syncthreads();
#pragma unroll
  for (int i = 0; i < 32; i += 8)
    out[(size_t)(n0 + y + i) * K + k0 + x] = f2bf(tile[x][y + i]);
}

// ---------------- 256x256 pipelined GEMM, 3 barriers/K-tile ----------------
// MODE 0: C -> bf16.  MODE 2: fused attention epilogue (N must be 1280;
// wave (wm,wn) owns 128 queries x head 4*bn+wn). K/V fragments come from
// pre-swizzled lane-coalesced kt2/vt2 buffers.
// CONV: blocks >= 60 instead run a f32->bf16 convert (overlaps BW with GEMM).
#define MFMA16(a, b, c) __builtin_amdgcn_mfma_f32_16x16x32_bf16(a, b, c, 0, 0, 0)
#define MFMA32(a, b, c) __builtin_amdgcn_mfma_f32_32x32x16_bf16(a, b, c, 0, 0, 0)

template <int MODE, int CONV>
__global__ __launch_bounds__(512, 2) void gemm256(
    const u16* __restrict__ A, const u16* __restrict__ Bt,
    u16* __restrict__ Cb, const u16* __restrict__ ktP, const u16* __restrict__ vtP,
    const float* __restrict__ convSrc, u16* __restrict__ convDst,
    int M, int N, int K) {
  const int tid = threadIdx.x;

  if (CONV) {
    if (blockIdx.x >= 60) {
      const float4* src = (const float4*)convSrc;
      ushort4* dst = (ushort4*)convDst;
      const long base = (long)(blockIdx.x - 60) * 4096 + tid;
#pragma unroll
      for (int k = 0; k < 8; ++k) {
        const float4 v = src[base + k * 512];
        ushort4 o;
        o.x = f2bf(v.x); o.y = f2bf(v.y); o.z = f2bf(v.z); o.w = f2bf(v.w);
        dst[base + k * 512] = o;
      }
      return;
    }
  }

  // 135168 B: staging view = As(64K) + Bs(64K); attn view = 8 x 16896 B Q-chunks
  __shared__ __align__(16) u16 smem[67584];
  u16* As = smem;
  u16* Bs = smem + 32768;

  const int w = tid >> 6, lane = tid & 63;
  const int lo = lane & 15, hi = lane >> 4;
  const int wm = w >> 2, wn = w & 3;

  const int nbn = N >> 8;
  int wg = blockIdx.x;
  if (!CONV) {  // bijective XCD swizzle (m204); skip for small CONV grids
    const int nwg = gridDim.x;
    const int q = nwg >> 3, r = nwg & 7;
    const int xcd = wg & 7, l = wg >> 3;
    wg = (xcd < r ? xcd * (q + 1) : r * (q + 1) + (xcd - r) * q) + l;
  }
  const int bm = wg / nbn, bn = wg % nbn;
  const int m0 = bm << 8, n0 = bn << 8;
  const int NT = K >> 6;

  const int sr = lane >> 3;
  const int sc8 = ((lane & 7) ^ sr) << 3;
  const u16* pA[2];
  const u16* pB[2];
#pragma unroll
  for (int i = 0; i < 2; ++i) {
    const int rr = (i * 8 + w) * 8 + sr;
    pA[i] = A + (size_t)(m0 + rr) * K + sc8;
    pB[i] = Bt + (size_t)(n0 + rr) * K + sc8;
  }
  const int ch0 = w * 512, ch1 = (8 + w) * 512;

#define STAGE_A(h, tt)                                                     \
  {                                                                        \
    const int ttc = ((tt) < NT) ? (tt) : (NT - 1);                         \
    u16* d = As + ((((tt)&1) * 2 + (h)) << 13);                            \
    const size_t off = (size_t)(h)*128 * K + (size_t)ttc * 64;             \
    gload16(pA[0] + off, d + ch0);                                         \
    gload16(pA[1] + off, d + ch1);                                         \
  }
#define STAGE_B(h, tt)                                                     \
  {                                                                        \
    const int ttc = ((tt) < NT) ? (tt) : (NT - 1);                         \
    u16* d = Bs + ((((tt)&1) * 2 + (h)) << 13);                            \
    const size_t off = (size_t)(h)*128 * K + (size_t)ttc * 64;             \
    gload16(pB[0] + off, d + ch0);                                         \
    gload16(pB[1] + off, d + ch1);                                         \
  }

  const int low0 = (lo << 7) | ((hi ^ (lo & 7)) << 4);
  const int low1 = (lo << 7) | (((4 | hi) ^ (lo & 7)) << 4);

  f32x4 acc[8][4];
#pragma unroll
  for (int i = 0; i < 8; ++i)
#pragma unroll
    for (int j = 0; j < 4; ++j) acc[i][j] = (f32x4){0.f, 0.f, 0.f, 0.f};

  STAGE_B(0, 0); STAGE_B(1, 0);
  STAGE_A(0, 0); STAGE_A(1, 0);
  STAGE_B(0, 1); STAGE_B(1, 1);

  const char* aSm = (const char*)As;
  const char* bSm = (const char*)Bs;

  for (int t = 0; t < NT; ++t) {
    const int p = t & 1;
    const int aBase = (p * 2 + wm) << 14;
    const int bBase = ((p * 2 + (wn >> 1)) << 14) + ((wn & 1) << 13);

    asm volatile("s_waitcnt vmcnt(4)" ::: "memory");
    asm volatile("s_barrier" ::: "memory");

    bf16x8 a0[4][2], a1[4][2], b0[2][2], b1[2][2];
    // ---- half A: q(0,0) + q(0,1); stage A(t+1) ----
#pragma unroll
    for (int mf = 0; mf < 4; ++mf) {
      a0[mf][0] = *(const bf16x8*)(aSm + aBase + (mf << 11) + low0);
      a0[mf][1] = *(const bf16x8*)(aSm + aBase + (mf << 11) + low1);
    }
#pragma unroll
    for (int nf = 0; nf < 2; ++nf) {
      b0[nf][0] = *(const bf16x8*)(bSm + bBase + (nf << 11) + low0);
      b0[nf][1] = *(const bf16x8*)(bSm + bBase + (nf << 11) + low1);
    }
    STAGE_A(0, t + 1);
    __builtin_amdgcn_s_setprio(1);
#pragma unroll
    for (int mf = 0; mf < 4; ++mf)
#pragma unroll
      for (int nf = 0; nf < 2; ++nf) {
        acc[mf][nf] = MFMA16(a0[mf][0], b0[nf][0], acc[mf][nf]);
        acc[mf][nf] = MFMA16(a0[mf][1], b0[nf][1], acc[mf][nf]);
      }
    __builtin_amdgcn_s_setprio(0);

#pragma unroll
    for (int nf = 0; nf < 2; ++nf) {
      b1[nf][0] = *(const bf16x8*)(bSm + bBase + (1 << 12) + (nf << 11) + low0);
      b1[nf][1] = *(const bf16x8*)(bSm + bBase + (1 << 12) + (nf << 11) + low1);
    }
    STAGE_A(1, t + 1);
    __builtin_amdgcn_s_setprio(1);
#pragma unroll
    for (int mf = 0; mf < 4; ++mf)
#pragma unroll
      for (int nf = 0; nf < 2; ++nf) {
        acc[mf][2 + nf] = MFMA16(a0[mf][0], b1[nf][0], acc[mf][2 + nf]);
        acc[mf][2 + nf] = MFMA16(a0[mf][1], b1[nf][1], acc[mf][2 + nf]);
      }
    __builtin_amdgcn_s_setprio(0);
    asm volatile("s_barrier" ::: "memory");

    // ---- half B: q(1,0) + q(1,1); stage B(t+2) ----
#pragma unroll
    for (int mf = 0; mf < 4; ++mf) {
      a1[mf][0] = *(const bf16x8*)(aSm + aBase + (1 << 13) + (mf << 11) + low0);
      a1[mf][1] = *(const bf16x8*)(aSm + aBase + (1 << 13) + (mf << 11) + low1);
    }
    STAGE_B(0, t + 2);
    __builtin_amdgcn_s_setprio(1);
#pragma unroll
    for (int mf = 0; mf < 4; ++mf)
#pragma unroll
      for (int nf = 0; nf < 2; ++nf) {
        acc[4 + mf][nf] = MFMA16(a1[mf][0], b0[nf][0], acc[4 + mf][nf]);
        acc[4 + mf][nf] = MFMA16(a1[mf][1], b0[nf][1], acc[4 + mf][nf]);
      }
    __builtin_amdgcn_s_setprio(0);

    STAGE_B(1, t + 2);
    __builtin_amdgcn_s_setprio(1);
#pragma unroll
    for (int mf = 0; mf < 4; ++mf)
#pragma unroll
      for (int nf = 0; nf < 2; ++nf) {
        acc[4 + mf][2 + nf] = MFMA16(a1[mf][0], b1[nf][0], acc[4 + mf][2 + nf]);
        acc[4 + mf][2 + nf] = MFMA16(a1[mf][1], b1[nf][1], acc[4 + mf][2 + nf]);
      }
    __builtin_amdgcn_s_setprio(0);
  }

  if (MODE != 2) {
    // ---- plain epilogue: bf16 C ----
#pragma unroll
    for (int g = 0; g < 2; ++g)
#pragma unroll
      for (int mf = 0; mf < 4; ++mf)
#pragma unroll
        for (int ng = 0; ng < 2; ++ng)
#pragma unroll
          for (int nfi = 0; nfi < 2; ++nfi) {
            const f32x4 v = acc[g * 4 + mf][ng * 2 + nfi];
            const int row0 = m0 + wm * 128 + g * 64 + mf * 16 + hi * 4;
            const int col = n0 + wn * 64 + ng * 32 + nfi * 16 + lo;
#pragma unroll
            for (int r = 0; r < 4; ++r)
              Cb[(size_t)(row0 + r) * N + col] = f2bf(v[r]);
          }
  } else {
    // ---- fused attention epilogue (coalesced kt2/vt2 fragment loads) ----
    const int l31 = lane & 31, hi5 = lane >> 5;
    const int h = bn * 4 + wn;
    const int b = m0 >> 12;
    const u16* ktb = ktP + (size_t)(b * 20 + h) * 6144;
    const u16* vtb = vtP + (size_t)(b * 20 + h) * 6144;

    // Hoist K fragments (coalesced: lane-contiguous 16B); latency hides
    // under the vmcnt(0) drain + Q-LDS writes below.
    bf16x8 kreg[3][4];
#pragma unroll
    for (int kf = 0; kf < 3; ++kf)
#pragma unroll
      for (int dc = 0; dc < 4; ++dc)
        kreg[kf][dc] = *(const bf16x8*)(ktb + (((kf << 2) | dc) << 9) + lane * 8);

    asm volatile("s_waitcnt vmcnt(0)" ::: "memory");
    __builtin_amdgcn_s_barrier();

    u16* qlds = smem + w * 8448;
#pragma unroll
    for (int g = 0; g < 2; ++g)
#pragma unroll
      for (int mf = 0; mf < 4; ++mf)
#pragma unroll
        for (int ng = 0; ng < 2; ++ng)
#pragma unroll
          for (int nfi = 0; nfi < 2; ++nfi) {
            const f32x4 v = acc[g * 4 + mf][ng * 2 + nfi];
            const int qrow = g * 64 + mf * 16 + hi * 4;
            const int d = ng * 32 + nfi * 16 + lo;
#pragma unroll
            for (int r = 0; r < 4; ++r) qlds[(qrow + r) * 66 + d] = f2bf(v[r]);
          }

    const int rowB = m0 + wm * 128;

#pragma unroll
    for (int pass = 0; pass < 2; ++pass) {
      bf16x8 qf0[4], qf1[4];
#pragma unroll
      for (int dc = 0; dc < 4; ++dc) {
        qf0[dc] = *(const bf16x8*)&qlds[(pass * 64 + l31) * 66 + dc * 16 + hi5 * 8];
        qf1[dc] = *(const bf16x8*)&qlds[(pass * 64 + 32 + l31) * 66 + dc * 16 + hi5 * 8];
      }

      f32x16 s0[3], s1[3];
#pragma unroll
      for (int kf = 0; kf < 3; ++kf)
#pragma unroll
        for (int r = 0; r < 16; ++r) { s0[kf][r] = 0.f; s1[kf][r] = 0.f; }

#pragma unroll
      for (int kf = 0; kf < 3; ++kf)
#pragma unroll
        for (int dc = 0; dc < 4; ++dc) {
          s0[kf] = MFMA32(kreg[kf][dc], qf0[dc], s0[kf]);
          s1[kf] = MFMA32(kreg[kf][dc], qf1[dc], s1[kf]);
        }

      float st0 = 0.f, si0 = 0.f, st1 = 0.f, si1 = 0.f;
#pragma unroll
      for (int kf = 0; kf < 3; ++kf)
#pragma unroll
        for (int r = 0; r < 16; ++r) {
          const int krem = (r & 3) + 8 * (r >> 2);
          const int k = kf * 32 + krem + 4 * hi5;
          const bool vtx = k < 77;
          const bool vip = (k >= 80) & (k < 84);
          const float e0 = (vtx | vip) ? __expf(s0[kf][r] * 0.125f) : 0.f;
          const float e1 = (vtx | vip) ? __expf(s1[kf][r] * 0.125f) : 0.f;
          s0[kf][r] = e0; s1[kf][r] = e1;
          st0 += vtx ? e0 : 0.f; si0 += vip ? e0 : 0.f;
          st1 += vtx ? e1 : 0.f; si1 += vip ? e1 : 0.f;
        }
      st0 += __shfl_xor(st0, 32); si0 += __shfl_xor(si0, 32);
      st1 += __shfl_xor(st1, 32); si1 += __shfl_xor(si1, 32);
      const float rt0 = __fdividef(1.f, st0), ri0 = __fdividef(1.f, si0);
      const float rt1 = __fdividef(1.f, st1), ri1 = __fdividef(1.f, si1);
#pragma unroll
      for (int kf = 0; kf < 3; ++kf)
#pragma unroll
        for (int r = 0; r < 16; ++r) {
          const int krem = (r & 3) + 8 * (r >> 2);
          const int k = kf * 32 + krem + 4 * hi5;
          const bool vip = (k >= 80) & (k < 84);
          s0[kf][r] *= vip ? ri0 : rt0;
          s1[kf][r] *= vip ? ri1 : rt1;
        }

#define PV_STORE(sA, qoff)                                                  \
      {                                                                     \
        f32x16 pacc[2];                                                     \
        _Pragma("unroll") for (int nf = 0; nf < 2; ++nf)                    \
        _Pragma("unroll") for (int r = 0; r < 16; ++r) pacc[nf][r] = 0.f;   \
        _Pragma("unroll") for (int ks = 0; ks < 6; ++ks) {                  \
          const int kf = ks >> 1;                                           \
          const int rb = (ks & 1) * 8;                                      \
          const u32 lo01 = cvtpk(sA[kf][rb + 0], sA[kf][rb + 1]);           \
          const u32 lo23 = cvtpk(sA[kf][rb + 2], sA[kf][rb + 3]);           \
          const u32 hi01 = cvtpk(sA[kf][rb + 4], sA[kf][rb + 5]);           \
          const u32 hi23 = cvtpk(sA[kf][rb + 6], sA[kf][rb + 7]);           \
          const u32 plo01 = __shfl_xor(lo01, 32);                           \
          const u32 plo23 = __shfl_xor(lo23, 32);                           \
          const u32 phi01 = __shfl_xor(hi01, 32);                           \
          const u32 phi23 = __shfl_xor(hi23, 32);                           \
          union { u32 u[4]; bf16x8 v; } pu;                                 \
          pu.u[0] = hi5 ? phi01 : lo01;                                     \
          pu.u[1] = hi5 ? phi23 : lo23;                                     \
          pu.u[2] = hi5 ? hi01 : plo01;                                     \
          pu.u[3] = hi5 ? hi23 : plo23;                                     \
          _Pragma("unroll") for (int nf = 0; nf < 2; ++nf) {                \
            const bf16x8 vb = *(const bf16x8*)(vtb +                        \
                ((((hi5 * 2 + nf) * 6 + ks) * 32 + l31) << 3));             \
            pacc[nf] = MFMA32(pu.v, vb, pacc[nf]);                          \
          }                                                                 \
        }                                                                   \
        _Pragma("unroll") for (int nf = 0; nf < 2; ++nf)                    \
        _Pragma("unroll") for (int r = 0; r < 16; ++r) {                    \
          const int row = rowB + pass * 64 + (qoff) +                       \
                          (r & 3) + 8 * (r >> 2) + 4 * hi5;                 \
          Cb[(size_t)row * 1280 + h * 64 + nf * 32 + l31] =                 \
              f2bf(pacc[nf][r]);                                            \
        }                                                                   \
      }

      PV_STORE(s0, 0)
      PV_STORE(s1, 32)
#undef PV_STORE
    }
  }
#undef STAGE_A
#undef STAGE_B
}

// ---------------- 128x128 GEMM, f32+bias out, 2 blocks/CU ----------------
__global__ __launch_bounds__(256, 2) void gemm128(
    const u16* __restrict__ A, const u16* __restrict__ Bt,
    float* __restrict__ Cf, const float* __restrict__ bias,
    int M, int N, int K) {
  __shared__ __align__(16) u16 smem[32768];  // As 32KB | Bs 32KB
  const int tid = threadIdx.x;
  const int w = tid >> 6, lane = tid & 63;
  const int lo = lane & 15, hi = lane >> 4;
  const int wm = w >> 1, wn = w & 1;

  const int nbn = N >> 7;
  int wg = blockIdx.x;
  {  // bijective XCD swizzle
    const int nwg = gridDim.x;
    const int q = nwg >> 3, r = nwg & 7;
    const int xcd = wg & 7, l = wg >> 3;
    wg = (xcd < r ? xcd * (q + 1) : r * (q + 1) + (xcd - r) * q) + l;
  }
  const int bm = wg / nbn, bn = wg % nbn;
  const int m0 = bm << 7, n0 = bn << 7;
  const int NT = K >> 6;

  const int sr = lane >> 3;
  const int sc8 = ((lane & 7) ^ sr) << 3;
  const u16 *pA[4], *pB[4];
#pragma unroll
  for (int j = 0; j < 4; ++j) {
    const int rr = (w + j * 4) * 8 + sr;
    pA[j] = A + (size_t)(m0 + rr) * K + sc8;
    pB[j] = Bt + (size_t)(n0 + rr) * K + sc8;
  }

#define STG128(tt)                                                         \
  {                                                                        \
    const int ttc = ((tt) < NT) ? (tt) : (NT - 1);                         \
    const int bofs = (((tt)&1) << 13); /* u16 units: buf * 8192 */         \
    const size_t off = (size_t)ttc * 64;                                   \
    _Pragma("unroll") for (int j = 0; j < 4; ++j) {                        \
      gload16(pA[j] + off, smem + bofs + (w + j * 4) * 512);               \
      gload16(pB[j] + off, smem + 16384 + bofs + (w + j * 4) * 512);       \
    }                                                                      \
  }

  const int low0 = (lo << 7) | ((hi ^ (lo & 7)) << 4);
  const int low1 = (lo << 7) | (((4 | hi) ^ (lo & 7)) << 4);
  const char* aSm = (const char*)smem;
  const char* bSm = (const char*)(smem + 16384);

  f32x4 acc[4][4];
#pragma unroll
  for (int i = 0; i < 4; ++i)
#pragma unroll
    for (int j = 0; j < 4; ++j) acc[i][j] = (f32x4){0.f, 0.f, 0.f, 0.f};

  STG128(0); STG128(1);

  for (int t = 0; t < NT; ++t) {
    const int aBase = ((t & 1) << 14) + (wm << 13);
    const int bBase = ((t & 1) << 14) + (wn << 13);

    asm volatile("s_waitcnt vmcnt(8)" ::: "memory");
    asm volatile("s_barrier" ::: "memory");

    bf16x8 a[4][2], b[4][2];
#pragma unroll
    for (int mf = 0; mf < 4; ++mf) {
      a[mf][0] = *(const bf16x8*)(aSm + aBase + (mf << 11) + low0);
      a[mf][1] = *(const bf16x8*)(aSm + aBase + (mf << 11) + low1);
    }
#pragma unroll
    for (int nf = 0; nf < 4; ++nf) {
      b[nf][0] = *(const bf16x8*)(bSm + bBase + (nf << 11) + low0);
      b[nf][1] = *(const bf16x8*)(bSm + bBase + (nf << 11) + low1);
    }
    // All reads must land before any wave restages this buffer (WAR).
    asm volatile("s_waitcnt lgkmcnt(0)" ::: "memory");
    __builtin_amdgcn_sched_barrier(0);
    asm volatile("s_barrier" ::: "memory");
    STG128(t + 2);
    __builtin_amdgcn_s_setprio(1);
#pragma unroll
    for (int mf = 0; mf < 4; ++mf)
#pragma unroll
      for (int nf = 0; nf < 4; ++nf) {
        acc[mf][nf] = MFMA16(a[mf][0], b[nf][0], acc[mf][nf]);
        acc[mf][nf] = MFMA16(a[mf][1], b[nf][1], acc[mf][nf]);
      }
    __builtin_amdgcn_s_setprio(0);
  }

#pragma unroll
  for (int mf = 0; mf < 4; ++mf)
#pragma unroll
    for (int nf = 0; nf < 4; ++nf) {
      const int row0 = m0 + wm * 64 + mf * 16 + hi * 4;
      const int col = n0 + wn * 64 + nf * 16 + lo;
      const float bb = bias[col];
#pragma unroll
      for (int r = 0; r < 4; ++r)
        Cf[(size_t)(row0 + r) * N + col] = acc[mf][nf][r] + bb;
    }
#undef STG128
}

// ------- build_kvt: lane-coalesced K/V fragment buffers per (b,h) -------
// kt2[bh][kf(3)][dc(4)][lane(64)][8]: = K[kf*32+(lane&31)][dc*16+(lane>>5)*8 + j]
// vt2[bh][hi5(2)][nf(2)][ks(6)][l31(32)][8]: = V[ks*16+hi5*8+j][nf*32+l31]
__global__ __launch_bounds__(256) void build_kvt(const u16* __restrict__ kvc,
                                                 u16* __restrict__ kt2,
                                                 u16* __restrict__ vt2) {
  __shared__ u16 Ls[96][72];
  const int tid = threadIdx.x;
  const int h = blockIdx.x % 20, b = blockIdx.x / 20;

  for (int idx = tid; idx < 96 * 8; idx += 256) {
    const int row = idx >> 3, c8 = (idx & 7) << 3;
    uint4 val = make_uint4(0, 0, 0, 0);
    if (row < 77)
      val = *(const uint4*)(kvc + (size_t)(b * 77 + row) * 5120 + 1280 + h * 64 + c8);
    else if (row >= 80 && row < 84)
      val = *(const uint4*)(kvc + (size_t)(640 + b * 4 + row - 80) * 5120 + 3840 + h * 64 + c8);
    *(uint4*)&Ls[row][c8] = val;
  }

  u16* kdst = kt2 + (size_t)blockIdx.x * 6144;
  for (int idx = tid; idx < 768; idx += 256) {
    const int lane_ = idx & 63;
    const int rest = idx >> 6;          // 0..11
    const int dc = rest & 3, kf = rest >> 2;
    const int key = kf * 32 + (lane_ & 31);
    const int dofs = dc * 16 + (lane_ >> 5) * 8;
    const u16* src;
    if (key < 77) src = kvc + (size_t)(b * 77 + key) * 5120 + h * 64 + dofs;
    else if (key >= 80 && key < 84)
      src = kvc + (size_t)(640 + b * 4 + key - 80) * 5120 + 2560 + h * 64 + dofs;
    else src = kvc + h * 64 + dofs;  // masked later; finite garbage ok
    *(uint4*)(kdst + idx * 8) = *(const uint4*)src;
  }
  __syncthreads();

  u16* vdst = vt2 + (size_t)blockIdx.x * 6144;
  for (int idx = tid; idx < 768; idx += 256) {
    const int l31 = idx & 31;
    const int rest = idx >> 5;          // 0..23
    const int ks = rest % 6;
    const int t = rest / 6;             // 0..3
    const int nf = t & 1, hi5 = t >> 1;
    u16 tmp[8];
#pragma unroll
    for (int j = 0; j < 8; ++j) tmp[j] = Ls[ks * 16 + hi5 * 8 + j][nf * 32 + l31];
    *(uint4*)(vdst + (((size_t)(hi5 * 2 + nf) * 6 + ks) * 32 + l31) * 8) = *(const uint4*)tmp;
  }
}

// ---------------- launch ----------------
extern "C" void kernel_launch(void* const* d_in, const int* in_sizes, int n_in,
                              void* d_out, int out_size, void* d_ws, size_t ws_size,
                              hipStream_t stream) {
  (void)in_sizes; (void)n_in; (void)out_size; (void)ws_size;
  const float* hs   = (const float*)d_in[0];
  const float* enc  = (const float*)d_in[1];
  const float* ip   = (const float*)d_in[2];
  const float* Wq   = (const float*)d_in[3];
  const float* Wk   = (const float*)d_in[4];
  const float* Wv   = (const float*)d_in[5];
  const float* Wkip = (const float*)d_in[6];
  const float* Wvip = (const float*)d_in[7];
  const float* Wo   = (const float*)d_in[8];
  const float* bo   = (const float*)d_in[9];
  float* out = (float*)d_out;

  // d_out (167.8 MB) as scratch: wq_t at start, hs_bf in second half
  // (both dead before the final f32 output write by O-proj).
  u16* wq_t  = (u16*)d_out;                        // 3,276,800 B
  u16* hs_bf = (u16*)d_out + 41943040;             // 83,886,080 B

  // ws layout. kvw/a_all overlap the attn region (dead before fused kernel).
  char* ws = (char*)d_ws;
  u16* kvc   = (u16*)(ws);                          // 15,728,640 B  [768][5120]
  u16* wo_t  = (u16*)(ws + 15728640);               //  3,276,800 B
  u16* kt2   = (u16*)(ws + 19005440);               //  1,966,080 B  [160][6144]
  u16* vt2   = (u16*)(ws + 20971520);               //  1,966,080 B  [160][6144]
  u16* attn  = (u16*)(ws + 22937600);               // 83,886,080 B
  u16* kvw   = (u16*)(ws + 22937600 + 3276800);     // 20,971,520 B (overlap) [5120][2048]
  u16* a_all = (u16*)(ws + 22937600 + 24248320);    //  3,145,728 B (overlap) [768][2048]

  // merged prep: a_all + 4x w4-transpose + 2x w2-transpose
  prep_all<<<14976, 256, 0, stream>>>(enc, ip, a_all, Wk, Wv, Wkip, Wvip, kvw,
                                      Wq, Wo, wq_t, wo_t);

  // fused K/V projections (blocks 0..59) + hs f32->bf16 convert (blocks 60..2619)
  gemm256<0, 1><<<2620, 512, 0, stream>>>(a_all, kvw, kvc, nullptr, nullptr,
                                          hs, hs_bf, 768, 5120, 2048);
  build_kvt<<<160, 256, 0, stream>>>(kvc, kt2, vt2);

  // Q-proj + attention fused: writes attn directly
  gemm256<2, 0><<<640, 512, 0, stream>>>(hs_bf, wq_t, attn, kt2, vt2,
                                         nullptr, nullptr, 32768, 1280, 1280);

  // O-proj + bias (f32 out): 128^2 tile, 2 blocks/CU, zero grid tail
  gemm128<<<2560, 256, 0, stream>>>(attn, wo_t, out, bo, 32768, 1280, 1280);
}